// Round 1
// baseline (795.742 us; speedup 1.0000x reference)
//
#include <hip/hip_runtime.h>

// MultiHeadAttention fwd: B=4, S=2048, DM=512, H=8, d=64.
// d_out = [Y | att_ws] in the HARNESS dtype, detected on-device (detect_k).
// Internal pipeline is bf16 MFMA throughout, softmax in exp2 domain
// (scale and mask pre-multiplied by log2e).
// Scratch ws: flag + maskf(fp32,premult) + biases bf16 + kh + vtb + ctx + wot.
// d_out scratch: qh at ob[0] (Y region, dead before final proj);
// wqt/wkt/wvt + bf16-staged Q/K/V at ob+4*YELEMS (att region, dead before
// attn overwrites att in either dtype mode).

typedef __bf16 bf16;
typedef __bf16 bf16x8 __attribute__((ext_vector_type(8)));
typedef float f32x4 __attribute__((ext_vector_type(4)));

constexpr int BATCH = 4;
constexpr int SEQ = 2048;
constexpr int DMODEL = 512;
constexpr int NHEAD = 8;
constexpr int HDIM = 64;
constexpr int MTOT = BATCH * SEQ;                  // 8192
constexpr long YELEMS = (long)MTOT * DMODEL;       // 4194304
constexpr long WELEMS = (long)DMODEL * DMODEL;     // 262144
constexpr float LOG2E = 1.44269504f;

__device__ __forceinline__ f32x4 mfma_bf16(bf16x8 a, bf16x8 b, f32x4 c) {
  return __builtin_amdgcn_mfma_f32_16x16x32_bf16(a, b, c, 0, 0, 0);
}

// ---------------------------------------------------------------- detector
// fp32 data: bits 14..7 are mantissa bits -> uniform (~25% in [0x60,0x9f]).
// bf16-pair data: bits 14..7 are the low element's exponent -> ~100% there.
__global__ void detect_k(const unsigned int* q, int* flag) {
  unsigned u = q[threadIdx.x];
  int e = (u >> 7) & 0xff;
  unsigned long long m = __ballot(e >= 0x60 && e <= 0x9f);
  if (threadIdx.x == 0) flag[0] = (__popcll(m) >= 48) ? 1 : 0;  // 1 = bf16
}

// --------------------------------------------------- fused Q/K/V -> bf16
// grid (YELEMS/(256*8), 3); y picks the tensor. 8 elems / thread.
__global__ __launch_bounds__(256) void cvt_qkv_k(
    const void* __restrict__ q, const void* __restrict__ k,
    const void* __restrict__ v, bf16* __restrict__ qb, bf16* __restrict__ kb,
    bf16* __restrict__ vb, const int* flag) {
  const int z = blockIdx.y;
  const void* src = (z == 0) ? q : (z == 1) ? k : v;
  bf16* dst = (z == 0) ? qb : (z == 1) ? kb : vb;
  const long i8 = ((long)blockIdx.x * 256 + threadIdx.x) * 8;
  if (*flag) {
    *(uint4*)(dst + i8) = *(const uint4*)((const bf16*)src + i8);
  } else {
    const float* s = (const float*)src + i8;
    const float4 a = *(const float4*)s;
    const float4 b = *(const float4*)(s + 4);
    bf16x8 o;
    o[0] = (bf16)a.x; o[1] = (bf16)a.y; o[2] = (bf16)a.z; o[3] = (bf16)a.w;
    o[4] = (bf16)b.x; o[5] = (bf16)b.y; o[6] = (bf16)b.z; o[7] = (bf16)b.w;
    *(bf16x8*)(dst + i8) = o;
  }
}

// ------------------------------------- mask (premult, fp32) + biases (bf16)
// grid ((8192+2048)/256) = 40 blocks. maskf = mask * (-1e9 * log2e).
__global__ void cvt_mb_k(const void* __restrict__ mask,
                         const void* __restrict__ b0,
                         const void* __restrict__ b1,
                         const void* __restrict__ b2,
                         const void* __restrict__ b3,
                         float* __restrict__ maskf, bf16* __restrict__ bias_c,
                         const int* flag) {
  const int f = *flag;
  const int i = blockIdx.x * 256 + threadIdx.x;
  if (i < BATCH * SEQ) {
    const float m = f ? (float)((const bf16*)mask)[i] : ((const float*)mask)[i];
    maskf[i] = m * (-1e9f * LOG2E);
  } else {
    const int j = i - BATCH * SEQ;  // 0..2047
    const int w = j >> 9;
    const void* s = (w == 0) ? b0 : (w == 1) ? b1 : (w == 2) ? b2 : b3;
    const int o = j & 511;
    bias_c[j] = f ? ((const bf16*)s)[o] : (bf16)((const float*)s)[o];
  }
}

// ------------------------------------------------- fused 4x W transpose
__global__ __launch_bounds__(256) void transpose_w4_k(
    const void* __restrict__ wq, const void* __restrict__ wk,
    const void* __restrict__ wv, const void* __restrict__ wo,
    bf16* __restrict__ wqt, bf16* __restrict__ wkt, bf16* __restrict__ wvt,
    bf16* __restrict__ wot, const int* flag) {
  __shared__ bf16 t[32][33];
  const int z = blockIdx.z;
  const void* w = (z == 0) ? wq : (z == 1) ? wk : (z == 2) ? wv : wo;
  bf16* wt = (z == 0) ? wqt : (z == 1) ? wkt : (z == 2) ? wvt : wot;
  const int f = *flag;
  const int bx = blockIdx.x * 32, by = blockIdx.y * 32;
  const int tx = threadIdx.x & 31, ty = threadIdx.x >> 5;
  for (int i = ty; i < 32; i += 8) {
    const long idx = (long)(by + i) * DMODEL + bx + tx;
    t[i][tx] = f ? ((const bf16*)w)[idx] : (bf16)((const float*)w)[idx];
  }
  __syncthreads();
  for (int i = ty; i < 32; i += 8)
    wt[(long)(bx + i) * DMODEL + by + tx] = t[tx][i];
}

// ------------------------------------------------------- 64x64-tile bf16 GEMM
// out = X[8192,512] @ Wt^T + bias. X bf16 always. Wt [n][k] bf16. bias bf16.
// mode 0: out[row][col] in HARNESS dtype (final Y)
// mode 1: out[b*H+h][s][d] bf16 ; mode 2: out[b*H+h][d][s] bf16
__global__ __launch_bounds__(256) void proj_gemm(
    const bf16* __restrict__ X, const bf16* __restrict__ Wt,
    const bf16* __restrict__ bias, void* __restrict__ out, int mode,
    const int* flag) {
  __shared__ __attribute__((aligned(16))) bf16 As[64][72];
  __shared__ __attribute__((aligned(16))) bf16 Bs[64][72];
  const int f = *flag;
  const int r0 = blockIdx.x * 64;
  const int c0 = blockIdx.y * 64;
  const int tid = threadIdx.x;
  const int wave = tid >> 6, lane = tid & 63;
  const int quad = lane >> 4, l16 = lane & 15;
  const int srow = tid >> 3, scb = (tid & 7) * 8;

  f32x4 acc[4] = {};
  for (int k0 = 0; k0 < DMODEL; k0 += 64) {
    __syncthreads();
    *(uint4*)&As[srow][scb] =
        *(const uint4*)(X + (long)(r0 + srow) * DMODEL + k0 + scb);
    *(uint4*)&As[srow + 32][scb] =
        *(const uint4*)(X + (long)(r0 + srow + 32) * DMODEL + k0 + scb);
    *(uint4*)&Bs[srow][scb] =
        *(const uint4*)(Wt + (long)(c0 + srow) * DMODEL + k0 + scb);
    *(uint4*)&Bs[srow + 32][scb] =
        *(const uint4*)(Wt + (long)(c0 + srow + 32) * DMODEL + k0 + scb);
    __syncthreads();
    const int m = wave * 16 + l16;
#pragma unroll
    for (int kk = 0; kk < 64; kk += 32) {
      bf16x8 a = *(const bf16x8*)&As[m][kk + quad * 8];
#pragma unroll
      for (int n = 0; n < 4; n++) {
        bf16x8 bb8 = *(const bf16x8*)&Bs[n * 16 + l16][kk + quad * 8];
        acc[n] = mfma_bf16(a, bb8, acc[n]);
      }
    }
  }

  __syncthreads();
  const bool f32out = (mode == 0) && !f;
#pragma unroll
  for (int n = 0; n < 4; n++) {
    const float bvv = (float)bias[c0 + n * 16 + l16];
#pragma unroll
    for (int r = 0; r < 4; r++) {
      const float v = acc[n][r] + bvv;
      const int ml = wave * 16 + quad * 4 + r;  // C/D: row = quad*4 + reg
      const int nl = n * 16 + l16;
      if (f32out) {
        ((float*)out)[(long)(r0 + ml) * DMODEL + c0 + nl] = v;
      } else if (mode == 2) {
        As[nl][ml] = (bf16)v;  // transposed stage [col][row]
      } else {
        As[ml][nl] = (bf16)v;  // row-major stage [row][col]
      }
    }
  }
  if (f32out) return;
  __syncthreads();

  const int rb = r0 >> 11;        // batch
  const int s0 = r0 & (SEQ - 1);  // seq base
  const int hh = c0 >> 6;         // head
  bf16* ob = (bf16*)out;
#pragma unroll
  for (int i = 0; i < 2; i++) {
    const int mrow = srow + i * 32;
    long idx;
    if (mode == 0) {
      idx = (long)(r0 + mrow) * DMODEL + c0 + scb;
    } else if (mode == 1) {
      idx = (((long)(rb * NHEAD + hh) * SEQ) + s0 + mrow) * HDIM + scb;
    } else {  // mode 2: [bh][d][s]
      idx = (((long)(rb * NHEAD + hh) * HDIM) + mrow) * SEQ + s0 + scb;
    }
    *(uint4*)(ob + idx) = *(const uint4*)&As[mrow][scb];
  }
}

// ------------------------------------------------------- two-pass attention
// exp2 domain: scores2 = qk * (0.125*log2e) + maskf  (maskf pre-multiplied).
__global__ __launch_bounds__(256) void attn_k(
    const bf16* __restrict__ qh, const bf16* __restrict__ kh,
    const bf16* __restrict__ vt, const float* __restrict__ maskf,
    bf16* __restrict__ attB, float* __restrict__ attF, bf16* __restrict__ ctx,
    const int* flag) {
  __shared__ __attribute__((aligned(16))) bf16 qs[64][72];
  __shared__ __attribute__((aligned(16))) bf16 ks[64][72];
  __shared__ __attribute__((aligned(16))) bf16 vs[64][72];  // [d][key]
  __shared__ __attribute__((aligned(16))) bf16 ps[64][72];  // [q][key]

  const int f = *flag;
  const int bh = blockIdx.y;
  const int bb = bh >> 3, hh = bh & 7;
  const int q0 = blockIdx.x * 64;
  const int tid = threadIdx.x;
  const int wave = tid >> 6, lane = tid & 63;
  const int quad = lane >> 4, l16 = lane & 15;
  const int srow = tid >> 3, scb = (tid & 7) * 8;
  const float scale2 = 0.125f * LOG2E;

  const bf16* qp = qh + ((long)bh * SEQ + q0) * HDIM;
  const bf16* kp = kh + (long)bh * SEQ * HDIM;
  const bf16* vp = vt + (long)bh * HDIM * SEQ;
  const float* mp = maskf + (long)bb * SEQ;

  *(uint4*)&qs[srow][scb] = *(const uint4*)(qp + (long)srow * HDIM + scb);
  *(uint4*)&qs[srow + 32][scb] =
      *(const uint4*)(qp + (long)(srow + 32) * HDIM + scb);

  float m_ln[4], l_ln[4];
#pragma unroll
  for (int r = 0; r < 4; r++) { m_ln[r] = -3e38f; l_ln[r] = 0.f; }
  const int mrow = wave * 16 + l16;

  // ---- pass 1: per-lane online (m, l) in log2 domain
  for (int t = 0; t < SEQ / 64; t++) {
    __syncthreads();
    const bf16* kt = kp + (long)t * 64 * HDIM;
    *(uint4*)&ks[srow][scb] = *(const uint4*)(kt + (long)srow * HDIM + scb);
    *(uint4*)&ks[srow + 32][scb] =
        *(const uint4*)(kt + (long)(srow + 32) * HDIM + scb);
    float mv[4];
#pragma unroll
    for (int n = 0; n < 4; n++) mv[n] = mp[t * 64 + n * 16 + l16];
    __syncthreads();
    f32x4 sc[4] = {};
#pragma unroll
    for (int kk = 0; kk < 64; kk += 32) {
      bf16x8 a = *(const bf16x8*)&qs[mrow][kk + quad * 8];
#pragma unroll
      for (int n = 0; n < 4; n++) {
        bf16x8 bb8 = *(const bf16x8*)&ks[n * 16 + l16][kk + quad * 8];
        sc[n] = mfma_bf16(a, bb8, sc[n]);
      }
    }
#pragma unroll
    for (int r = 0; r < 4; r++) {
      const float v0 = fmaf(sc[0][r], scale2, mv[0]);
      const float v1 = fmaf(sc[1][r], scale2, mv[1]);
      const float v2 = fmaf(sc[2][r], scale2, mv[2]);
      const float v3 = fmaf(sc[3][r], scale2, mv[3]);
      const float mx = fmaxf(fmaxf(v0, v1), fmaxf(v2, v3));
      const float mnew = fmaxf(m_ln[r], mx);
      l_ln[r] = l_ln[r] * exp2f(m_ln[r] - mnew) + exp2f(v0 - mnew) +
                exp2f(v1 - mnew) + exp2f(v2 - mnew) + exp2f(v3 - mnew);
      m_ln[r] = mnew;
    }
  }

  // ---- merge across the 16 lanes of each C-row
  float m_i[4], rcl[4];
#pragma unroll
  for (int r = 0; r < 4; r++) {
    float mr = m_ln[r];
#pragma unroll
    for (int o = 1; o < 16; o <<= 1) mr = fmaxf(mr, __shfl_xor(mr, o, 64));
    float lr = l_ln[r] * exp2f(m_ln[r] - mr);
#pragma unroll
    for (int o = 1; o < 16; o <<= 1) lr += __shfl_xor(lr, o, 64);
    m_i[r] = mr;
    rcl[r] = 1.f / lr;
  }

  // ---- pass 2
  f32x4 oacc[4] = {};
  const long abase = ((long)bh * SEQ + q0) * SEQ;

  for (int t = 0; t < SEQ / 64; t++) {
    __syncthreads();
    const bf16* kt = kp + (long)t * 64 * HDIM;
    *(uint4*)&ks[srow][scb] = *(const uint4*)(kt + (long)srow * HDIM + scb);
    *(uint4*)&ks[srow + 32][scb] =
        *(const uint4*)(kt + (long)(srow + 32) * HDIM + scb);
    *(uint4*)&vs[srow][scb] =
        *(const uint4*)(vp + (long)srow * SEQ + t * 64 + scb);
    *(uint4*)&vs[srow + 32][scb] =
        *(const uint4*)(vp + (long)(srow + 32) * SEQ + t * 64 + scb);
    float mv[4];
#pragma unroll
    for (int n = 0; n < 4; n++) mv[n] = mp[t * 64 + n * 16 + l16];
    __syncthreads();
    f32x4 sc[4] = {};
#pragma unroll
    for (int kk = 0; kk < 64; kk += 32) {
      bf16x8 a = *(const bf16x8*)&qs[mrow][kk + quad * 8];
#pragma unroll
      for (int n = 0; n < 4; n++) {
        bf16x8 bb8 = *(const bf16x8*)&ks[n * 16 + l16][kk + quad * 8];
        sc[n] = mfma_bf16(a, bb8, sc[n]);
      }
    }
#pragma unroll
    for (int r = 0; r < 4; r++) {
      const int prow = wave * 16 + quad * 4 + r;
#pragma unroll
      for (int n = 0; n < 4; n++) {
        const float p =
            exp2f(fmaf(sc[n][r], scale2, mv[n]) - m_i[r]) * rcl[r];
        ps[prow][n * 16 + l16] = (bf16)p;
        if (!f) attF[abase + (long)prow * SEQ + t * 64 + n * 16 + l16] = p;
      }
    }
    __syncthreads();
#pragma unroll
    for (int kk = 0; kk < 64; kk += 32) {
      bf16x8 a = *(const bf16x8*)&ps[wave * 16 + l16][kk + quad * 8];
#pragma unroll
      for (int n = 0; n < 4; n++) {
        bf16x8 bb8 = *(const bf16x8*)&vs[n * 16 + l16][kk + quad * 8];
        oacc[n] = mfma_bf16(a, bb8, oacc[n]);
      }
    }
    if (f) {
#pragma unroll
      for (int i = 0; i < 2; i++) {
        const int ci = lane + i * 64;
        const int rr = ci >> 3, cc = (ci & 7) * 8;
        *(uint4*)(attB + abase + (long)(wave * 16 + rr) * SEQ + t * 64 + cc) =
            *(const uint4*)&ps[wave * 16 + rr][cc];
      }
    }
  }

  // ---- ctx [B][S][DM] bf16
#pragma unroll
  for (int n = 0; n < 4; n++) {
#pragma unroll
    for (int r = 0; r < 4; r++) {
      const int s = q0 + wave * 16 + quad * 4 + r;
      const int d = n * 16 + l16;
      ctx[((long)bb * SEQ + s) * DMODEL + hh * HDIM + d] = (bf16)oacc[n][r];
    }
  }
}

// ----------------------------------------------------------------- launcher
extern "C" void kernel_launch(void* const* d_in, const int* in_sizes, int n_in,
                              void* d_out, int out_size, void* d_ws,
                              size_t ws_size, hipStream_t stream) {
  const void* Q = d_in[0];
  const void* K = d_in[1];
  const void* V = d_in[2];
  const void* mask = d_in[3];
  const void* Wq = d_in[4];
  const void* bq = d_in[5];
  const void* Wk = d_in[6];
  const void* bk = d_in[7];
  const void* Wv = d_in[8];
  const void* bv = d_in[9];
  const void* Wo = d_in[10];
  const void* bo = d_in[11];

  char* ob = (char*)d_out;
  bf16* attB = (bf16*)(ob + 2 * YELEMS);    // bf16-mode att base
  float* attF = (float*)(ob + 4 * YELEMS);  // fp32-mode att base
  bf16* qh = (bf16*)ob;  // Y region scratch, dead before final proj

  // staging in att region (safe both modes; dead before attn writes att)
  bf16* stg = (bf16*)(ob + 4 * YELEMS);
  bf16* wqt = stg;
  bf16* wkt = wqt + WELEMS;
  bf16* wvt = wkt + WELEMS;
  bf16* qb = wvt + WELEMS;   // bf16-staged Q
  bf16* kb = qb + YELEMS;    // bf16-staged K
  bf16* vb = kb + YELEMS;    // bf16-staged V

  // ws: flag + premult fp32 mask + bf16 biases + persistent bf16 buffers
  char* wb = (char*)d_ws;
  int* flag = (int*)wb;
  float* maskf = (float*)(wb + 16);              // 8192 fp32 = 32 KB
  bf16* bias_c = (bf16*)(wb + 16 + 32768);       // 4*512 bf16 = 4 KB
  bf16* bq_c = bias_c;
  bf16* bk_c = bq_c + 512;
  bf16* bv_c = bk_c + 512;
  bf16* bo_c = bv_c + 512;
  bf16* kh = (bf16*)(wb + 16 + 32768 + 4096);
  bf16* vtb = kh + YELEMS;
  bf16* ctx = vtb + YELEMS;
  bf16* wot = ctx + YELEMS;

  dim3 tb(256);
  detect_k<<<1, 64, 0, stream>>>((const unsigned int*)Q, flag);

  cvt_mb_k<<<40, tb, 0, stream>>>(mask, bq, bk, bv, bo, maskf, bias_c, flag);
  cvt_qkv_k<<<dim3(YELEMS / (256 * 8), 3), tb, 0, stream>>>(Q, K, V, qb, kb,
                                                            vb, flag);
  transpose_w4_k<<<dim3(DMODEL / 32, DMODEL / 32, 4), tb, 0, stream>>>(
      Wq, Wk, Wv, Wo, wqt, wkt, wvt, wot, flag);

  dim3 gp(MTOT / 64, DMODEL / 64);
  proj_gemm<<<gp, tb, 0, stream>>>(qb, wqt, bq_c, qh, 1, flag);
  proj_gemm<<<gp, tb, 0, stream>>>(kb, wkt, bk_c, kh, 1, flag);
  proj_gemm<<<gp, tb, 0, stream>>>(vb, wvt, bv_c, vtb, 2, flag);

  attn_k<<<dim3(SEQ / 64, BATCH * NHEAD), tb, 0, stream>>>(
      qh, kh, vtb, maskf, attB, attF, ctx, flag);

  proj_gemm<<<gp, tb, 0, stream>>>(ctx, wot, bo_c, d_out, 0, flag);
}

// Round 2
// 765.796 us; speedup vs baseline: 1.0391x; 1.0391x over previous
//
#include <hip/hip_runtime.h>

// MultiHeadAttention fwd: B=4, S=2048, DM=512, H=8, d=64.
// d_out = [Y | att_ws] in the HARNESS dtype, detected on-device (detect_k).
// Internal pipeline is bf16 MFMA throughout, softmax in exp2 domain
// (scale and mask pre-multiplied by log2e).
// attn_k: Q-tile 128, 512 threads, Q fragments in registers, async-STAGE
// (K/V tile t+1 global->reg during tile t compute), 2 barriers/tile,
// ps (P matrix LDS) is wave-private so PV needs no extra barrier.
// Scratch ws: flag + maskf(fp32,premult) + biases bf16 + kh + vtb + ctx + wot.
// d_out scratch: qh at ob[0] (Y region, dead before final proj);
// wqt/wkt/wvt + bf16-staged Q/K/V at ob+4*YELEMS (att region, dead before
// attn overwrites att in either dtype mode).

typedef __bf16 bf16;
typedef __bf16 bf16x8 __attribute__((ext_vector_type(8)));
typedef float f32x4 __attribute__((ext_vector_type(4)));

constexpr int BATCH = 4;
constexpr int SEQ = 2048;
constexpr int DMODEL = 512;
constexpr int NHEAD = 8;
constexpr int HDIM = 64;
constexpr int MTOT = BATCH * SEQ;                  // 8192
constexpr long YELEMS = (long)MTOT * DMODEL;       // 4194304
constexpr long WELEMS = (long)DMODEL * DMODEL;     // 262144
constexpr float LOG2E = 1.44269504f;

__device__ __forceinline__ f32x4 mfma_bf16(bf16x8 a, bf16x8 b, f32x4 c) {
  return __builtin_amdgcn_mfma_f32_16x16x32_bf16(a, b, c, 0, 0, 0);
}

// ---------------------------------------------------------------- detector
// fp32 data: bits 14..7 are mantissa bits -> uniform (~25% in [0x60,0x9f]).
// bf16-pair data: bits 14..7 are the low element's exponent -> ~100% there.
__global__ void detect_k(const unsigned int* q, int* flag) {
  unsigned u = q[threadIdx.x];
  int e = (u >> 7) & 0xff;
  unsigned long long m = __ballot(e >= 0x60 && e <= 0x9f);
  if (threadIdx.x == 0) flag[0] = (__popcll(m) >= 48) ? 1 : 0;  // 1 = bf16
}

// --------------------------------------------------- fused Q/K/V -> bf16
// grid (YELEMS/(256*8), 3); y picks the tensor. 8 elems / thread.
__global__ __launch_bounds__(256) void cvt_qkv_k(
    const void* __restrict__ q, const void* __restrict__ k,
    const void* __restrict__ v, bf16* __restrict__ qb, bf16* __restrict__ kb,
    bf16* __restrict__ vb, const int* flag) {
  const int z = blockIdx.y;
  const void* src = (z == 0) ? q : (z == 1) ? k : v;
  bf16* dst = (z == 0) ? qb : (z == 1) ? kb : vb;
  const long i8 = ((long)blockIdx.x * 256 + threadIdx.x) * 8;
  if (*flag) {
    *(uint4*)(dst + i8) = *(const uint4*)((const bf16*)src + i8);
  } else {
    const float* s = (const float*)src + i8;
    const float4 a = *(const float4*)s;
    const float4 b = *(const float4*)(s + 4);
    bf16x8 o;
    o[0] = (bf16)a.x; o[1] = (bf16)a.y; o[2] = (bf16)a.z; o[3] = (bf16)a.w;
    o[4] = (bf16)b.x; o[5] = (bf16)b.y; o[6] = (bf16)b.z; o[7] = (bf16)b.w;
    *(bf16x8*)(dst + i8) = o;
  }
}

// ------------------------------------- mask (premult, fp32) + biases (bf16)
// grid ((8192+2048)/256) = 40 blocks. maskf = mask * (-1e9 * log2e).
__global__ void cvt_mb_k(const void* __restrict__ mask,
                         const void* __restrict__ b0,
                         const void* __restrict__ b1,
                         const void* __restrict__ b2,
                         const void* __restrict__ b3,
                         float* __restrict__ maskf, bf16* __restrict__ bias_c,
                         const int* flag) {
  const int f = *flag;
  const int i = blockIdx.x * 256 + threadIdx.x;
  if (i < BATCH * SEQ) {
    const float m = f ? (float)((const bf16*)mask)[i] : ((const float*)mask)[i];
    maskf[i] = m * (-1e9f * LOG2E);
  } else {
    const int j = i - BATCH * SEQ;  // 0..2047
    const int w = j >> 9;
    const void* s = (w == 0) ? b0 : (w == 1) ? b1 : (w == 2) ? b2 : b3;
    const int o = j & 511;
    bias_c[j] = f ? ((const bf16*)s)[o] : (bf16)((const float*)s)[o];
  }
}

// ------------------------------------------------- fused 4x W transpose
__global__ __launch_bounds__(256) void transpose_w4_k(
    const void* __restrict__ wq, const void* __restrict__ wk,
    const void* __restrict__ wv, const void* __restrict__ wo,
    bf16* __restrict__ wqt, bf16* __restrict__ wkt, bf16* __restrict__ wvt,
    bf16* __restrict__ wot, const int* flag) {
  __shared__ bf16 t[32][33];
  const int z = blockIdx.z;
  const void* w = (z == 0) ? wq : (z == 1) ? wk : (z == 2) ? wv : wo;
  bf16* wt = (z == 0) ? wqt : (z == 1) ? wkt : (z == 2) ? wvt : wot;
  const int f = *flag;
  const int bx = blockIdx.x * 32, by = blockIdx.y * 32;
  const int tx = threadIdx.x & 31, ty = threadIdx.x >> 5;
  for (int i = ty; i < 32; i += 8) {
    const long idx = (long)(by + i) * DMODEL + bx + tx;
    t[i][tx] = f ? ((const bf16*)w)[idx] : (bf16)((const float*)w)[idx];
  }
  __syncthreads();
  for (int i = ty; i < 32; i += 8)
    wt[(long)(bx + i) * DMODEL + by + tx] = t[tx][i];
}

// ------------------------------------------------------- 64x64-tile bf16 GEMM
// out = X[8192,512] @ Wt^T + bias. X bf16 always. Wt [n][k] bf16. bias bf16.
// mode 0: out[row][col] in HARNESS dtype (final Y)
// mode 1: out[b*H+h][s][d] bf16 ; mode 2: out[b*H+h][d][s] bf16
__global__ __launch_bounds__(256) void proj_gemm(
    const bf16* __restrict__ X, const bf16* __restrict__ Wt,
    const bf16* __restrict__ bias, void* __restrict__ out, int mode,
    const int* flag) {
  __shared__ __attribute__((aligned(16))) bf16 As[64][72];
  __shared__ __attribute__((aligned(16))) bf16 Bs[64][72];
  const int f = *flag;
  const int r0 = blockIdx.x * 64;
  const int c0 = blockIdx.y * 64;
  const int tid = threadIdx.x;
  const int wave = tid >> 6, lane = tid & 63;
  const int quad = lane >> 4, l16 = lane & 15;
  const int srow = tid >> 3, scb = (tid & 7) * 8;

  f32x4 acc[4] = {};
  for (int k0 = 0; k0 < DMODEL; k0 += 64) {
    __syncthreads();
    *(uint4*)&As[srow][scb] =
        *(const uint4*)(X + (long)(r0 + srow) * DMODEL + k0 + scb);
    *(uint4*)&As[srow + 32][scb] =
        *(const uint4*)(X + (long)(r0 + srow + 32) * DMODEL + k0 + scb);
    *(uint4*)&Bs[srow][scb] =
        *(const uint4*)(Wt + (long)(c0 + srow) * DMODEL + k0 + scb);
    *(uint4*)&Bs[srow + 32][scb] =
        *(const uint4*)(Wt + (long)(c0 + srow + 32) * DMODEL + k0 + scb);
    __syncthreads();
    const int m = wave * 16 + l16;
#pragma unroll
    for (int kk = 0; kk < 64; kk += 32) {
      bf16x8 a = *(const bf16x8*)&As[m][kk + quad * 8];
#pragma unroll
      for (int n = 0; n < 4; n++) {
        bf16x8 bb8 = *(const bf16x8*)&Bs[n * 16 + l16][kk + quad * 8];
        acc[n] = mfma_bf16(a, bb8, acc[n]);
      }
    }
  }

  __syncthreads();
  const bool f32out = (mode == 0) && !f;
#pragma unroll
  for (int n = 0; n < 4; n++) {
    const float bvv = (float)bias[c0 + n * 16 + l16];
#pragma unroll
    for (int r = 0; r < 4; r++) {
      const float v = acc[n][r] + bvv;
      const int ml = wave * 16 + quad * 4 + r;  // C/D: row = quad*4 + reg
      const int nl = n * 16 + l16;
      if (f32out) {
        ((float*)out)[(long)(r0 + ml) * DMODEL + c0 + nl] = v;
      } else if (mode == 2) {
        As[nl][ml] = (bf16)v;  // transposed stage [col][row]
      } else {
        As[ml][nl] = (bf16)v;  // row-major stage [row][col]
      }
    }
  }
  if (f32out) return;
  __syncthreads();

  const int rb = r0 >> 11;        // batch
  const int s0 = r0 & (SEQ - 1);  // seq base
  const int hh = c0 >> 6;         // head
  bf16* ob = (bf16*)out;
#pragma unroll
  for (int i = 0; i < 2; i++) {
    const int mrow = srow + i * 32;
    long idx;
    if (mode == 0) {
      idx = (long)(r0 + mrow) * DMODEL + c0 + scb;
    } else if (mode == 1) {
      idx = (((long)(rb * NHEAD + hh) * SEQ) + s0 + mrow) * HDIM + scb;
    } else {  // mode 2: [bh][d][s]
      idx = (((long)(rb * NHEAD + hh) * HDIM) + mrow) * SEQ + s0 + scb;
    }
    *(uint4*)(ob + idx) = *(const uint4*)&As[mrow][scb];
  }
}

// ------------------------------------------------------- two-pass attention
// Q-tile 128, 512 threads (8 waves, each owning 16 q-rows).
// exp2 domain: scores2 = qk * (0.125*log2e) + maskf  (maskf pre-premult).
// Async-STAGE: next K/V tile is loaded to regs while current tile computes.
__global__ __launch_bounds__(512) void attn_k(
    const bf16* __restrict__ qh, const bf16* __restrict__ kh,
    const bf16* __restrict__ vt, const float* __restrict__ maskf,
    bf16* __restrict__ attB, float* __restrict__ attF, bf16* __restrict__ ctx,
    const int* flag) {
  __shared__ __attribute__((aligned(16))) bf16 ks[64][72];
  __shared__ __attribute__((aligned(16))) bf16 vs[64][72];   // [d][key]
  __shared__ __attribute__((aligned(16))) bf16 ps[128][72];  // [q][key]
  __shared__ float msk[SEQ];                                 // premult mask row

  const int f = *flag;
  const int bh = blockIdx.y;
  const int bb = bh >> 3, hh = bh & 7;
  const int q0 = blockIdx.x * 128;
  const int tid = threadIdx.x;
  const int wave = tid >> 6, lane = tid & 63;
  const int quad = lane >> 4, l16 = lane & 15;
  const int srow = tid >> 3;        // 0..63
  const int scb = (tid & 7) * 8;
  const float scale2 = 0.125f * LOG2E;
  constexpr int NT = SEQ / 64;

  const bf16* qp = qh + ((long)bh * SEQ + q0) * HDIM;
  const bf16* kp = kh + (long)bh * SEQ * HDIM;
  const bf16* vp = vt + (long)bh * HDIM * SEQ;
  const float* mp = maskf + (long)bb * SEQ;

  // mask row -> LDS (once). 2048 floats / 512 threads = 1 float4 each.
  ((float4*)msk)[tid] = ((const float4*)mp)[tid];

  // Q fragments in registers (A-frag: row = wave*16+l16, cols quad*8..+7).
  const int rq = wave * 16 + l16;
  const bf16x8 qa0 = *(const bf16x8*)(qp + (long)rq * HDIM + quad * 8);
  const bf16x8 qa1 = *(const bf16x8*)(qp + (long)rq * HDIM + 32 + quad * 8);

  // prologue: K tile 0 -> regs
  uint4 kreg = *(const uint4*)(kp + (long)srow * HDIM + scb);

  float m_ln[4], l_ln[4];
#pragma unroll
  for (int r = 0; r < 4; r++) { m_ln[r] = -3e38f; l_ln[r] = 0.f; }

  // ---- pass 1: per-lane online (m, l) in log2 domain
  for (int t = 0; t < NT; t++) {
    __syncthreads();  // prev tile's ks reads done
    *(uint4*)&ks[srow][scb] = kreg;
    if (t + 1 < NT)
      kreg = *(const uint4*)(kp + ((long)(t + 1) * 64 + srow) * HDIM + scb);
    __syncthreads();  // ks (and at t=0, msk) ready
    float mv[4];
#pragma unroll
    for (int n = 0; n < 4; n++) mv[n] = msk[t * 64 + n * 16 + l16];
    f32x4 sc[4] = {};
#pragma unroll
    for (int n = 0; n < 4; n++) {
      bf16x8 b0 = *(const bf16x8*)&ks[n * 16 + l16][quad * 8];
      sc[n] = mfma_bf16(qa0, b0, sc[n]);
    }
#pragma unroll
    for (int n = 0; n < 4; n++) {
      bf16x8 b1 = *(const bf16x8*)&ks[n * 16 + l16][32 + quad * 8];
      sc[n] = mfma_bf16(qa1, b1, sc[n]);
    }
#pragma unroll
    for (int r = 0; r < 4; r++) {
      const float v0 = fmaf(sc[0][r], scale2, mv[0]);
      const float v1 = fmaf(sc[1][r], scale2, mv[1]);
      const float v2 = fmaf(sc[2][r], scale2, mv[2]);
      const float v3 = fmaf(sc[3][r], scale2, mv[3]);
      const float mx = fmaxf(fmaxf(v0, v1), fmaxf(v2, v3));
      const float mnew = fmaxf(m_ln[r], mx);
      l_ln[r] = l_ln[r] * exp2f(m_ln[r] - mnew) + exp2f(v0 - mnew) +
                exp2f(v1 - mnew) + exp2f(v2 - mnew) + exp2f(v3 - mnew);
      m_ln[r] = mnew;
    }
  }

  // pass-2 prologue loads issued BEFORE the merge (hide latency under shfls)
  kreg = *(const uint4*)(kp + (long)srow * HDIM + scb);
  uint4 vreg = *(const uint4*)(vp + (long)srow * SEQ + scb);

  // ---- merge across the 16 lanes of each C-row
  float m_i[4], rcl[4];
#pragma unroll
  for (int r = 0; r < 4; r++) {
    float mr = m_ln[r];
#pragma unroll
    for (int o = 1; o < 16; o <<= 1) mr = fmaxf(mr, __shfl_xor(mr, o, 64));
    float lr = l_ln[r] * exp2f(m_ln[r] - mr);
#pragma unroll
    for (int o = 1; o < 16; o <<= 1) lr += __shfl_xor(lr, o, 64);
    m_i[r] = mr;
    rcl[r] = 1.f / lr;
  }

  // ---- pass 2
  f32x4 oacc[4] = {};
  const long abase = ((long)bh * SEQ + q0) * SEQ;

  for (int t = 0; t < NT; t++) {
    __syncthreads();  // prev tile's ks/vs reads done
    *(uint4*)&ks[srow][scb] = kreg;
    *(uint4*)&vs[srow][scb] = vreg;
    if (t + 1 < NT) {
      kreg = *(const uint4*)(kp + ((long)(t + 1) * 64 + srow) * HDIM + scb);
      vreg = *(const uint4*)(vp + (long)srow * SEQ + (t + 1) * 64 + scb);
    }
    __syncthreads();  // ks/vs ready
    float mv[4];
#pragma unroll
    for (int n = 0; n < 4; n++) mv[n] = msk[t * 64 + n * 16 + l16];
    f32x4 sc[4] = {};
#pragma unroll
    for (int n = 0; n < 4; n++) {
      bf16x8 b0 = *(const bf16x8*)&ks[n * 16 + l16][quad * 8];
      sc[n] = mfma_bf16(qa0, b0, sc[n]);
    }
#pragma unroll
    for (int n = 0; n < 4; n++) {
      bf16x8 b1 = *(const bf16x8*)&ks[n * 16 + l16][32 + quad * 8];
      sc[n] = mfma_bf16(qa1, b1, sc[n]);
    }
#pragma unroll
    for (int r = 0; r < 4; r++) {
      const int prow = wave * 16 + quad * 4 + r;
#pragma unroll
      for (int n = 0; n < 4; n++) {
        const float p =
            exp2f(fmaf(sc[n][r], scale2, mv[n]) - m_i[r]) * rcl[r];
        ps[prow][n * 16 + l16] = (bf16)p;
        if (!f) attF[abase + (long)prow * SEQ + t * 64 + n * 16 + l16] = p;
      }
    }
    // no barrier: ps rows wave*16..wave*16+15 are written AND read only by
    // this wave; compiler lgkmcnt ordering covers the LDS RAW.
#pragma unroll
    for (int kk = 0; kk < 64; kk += 32) {
      bf16x8 a = *(const bf16x8*)&ps[wave * 16 + l16][kk + quad * 8];
#pragma unroll
      for (int n = 0; n < 4; n++) {
        bf16x8 bb8 = *(const bf16x8*)&vs[n * 16 + l16][kk + quad * 8];
        oacc[n] = mfma_bf16(a, bb8, oacc[n]);
      }
    }
    if (f) {
#pragma unroll
      for (int i = 0; i < 2; i++) {
        const int ci = lane + i * 64;
        const int rr = ci >> 3, cc = (ci & 7) * 8;
        *(uint4*)(attB + abase + (long)(wave * 16 + rr) * SEQ + t * 64 + cc) =
            *(const uint4*)&ps[wave * 16 + rr][cc];
      }
    }
  }

  // ---- ctx [B][S][DM] bf16
#pragma unroll
  for (int n = 0; n < 4; n++) {
#pragma unroll
    for (int r = 0; r < 4; r++) {
      const int s = q0 + wave * 16 + quad * 4 + r;
      const int d = n * 16 + l16;
      ctx[((long)bb * SEQ + s) * DMODEL + hh * HDIM + d] = (bf16)oacc[n][r];
    }
  }
}

// ----------------------------------------------------------------- launcher
extern "C" void kernel_launch(void* const* d_in, const int* in_sizes, int n_in,
                              void* d_out, int out_size, void* d_ws,
                              size_t ws_size, hipStream_t stream) {
  const void* Q = d_in[0];
  const void* K = d_in[1];
  const void* V = d_in[2];
  const void* mask = d_in[3];
  const void* Wq = d_in[4];
  const void* bq = d_in[5];
  const void* Wk = d_in[6];
  const void* bk = d_in[7];
  const void* Wv = d_in[8];
  const void* bv = d_in[9];
  const void* Wo = d_in[10];
  const void* bo = d_in[11];

  char* ob = (char*)d_out;
  bf16* attB = (bf16*)(ob + 2 * YELEMS);    // bf16-mode att base
  float* attF = (float*)(ob + 4 * YELEMS);  // fp32-mode att base
  bf16* qh = (bf16*)ob;  // Y region scratch, dead before final proj

  // staging in att region (safe both modes; dead before attn writes att)
  bf16* stg = (bf16*)(ob + 4 * YELEMS);
  bf16* wqt = stg;
  bf16* wkt = wqt + WELEMS;
  bf16* wvt = wkt + WELEMS;
  bf16* qb = wvt + WELEMS;   // bf16-staged Q
  bf16* kb = qb + YELEMS;    // bf16-staged K
  bf16* vb = kb + YELEMS;    // bf16-staged V

  // ws: flag + premult fp32 mask + bf16 biases + persistent bf16 buffers
  char* wb = (char*)d_ws;
  int* flag = (int*)wb;
  float* maskf = (float*)(wb + 16);              // 8192 fp32 = 32 KB
  bf16* bias_c = (bf16*)(wb + 16 + 32768);       // 4*512 bf16 = 4 KB
  bf16* bq_c = bias_c;
  bf16* bk_c = bq_c + 512;
  bf16* bv_c = bk_c + 512;
  bf16* bo_c = bv_c + 512;
  bf16* kh = (bf16*)(wb + 16 + 32768 + 4096);
  bf16* vtb = kh + YELEMS;
  bf16* ctx = vtb + YELEMS;
  bf16* wot = ctx + YELEMS;

  dim3 tb(256);
  detect_k<<<1, 64, 0, stream>>>((const unsigned int*)Q, flag);

  cvt_mb_k<<<40, tb, 0, stream>>>(mask, bq, bk, bv, bo, maskf, bias_c, flag);
  cvt_qkv_k<<<dim3(YELEMS / (256 * 8), 3), tb, 0, stream>>>(Q, K, V, qb, kb,
                                                            vb, flag);
  transpose_w4_k<<<dim3(DMODEL / 32, DMODEL / 32, 4), tb, 0, stream>>>(
      Wq, Wk, Wv, Wo, wqt, wkt, wvt, wot, flag);

  dim3 gp(MTOT / 64, DMODEL / 64);
  proj_gemm<<<gp, tb, 0, stream>>>(qb, wqt, bq_c, qh, 1, flag);
  proj_gemm<<<gp, tb, 0, stream>>>(kb, wkt, bk_c, kh, 1, flag);
  proj_gemm<<<gp, tb, 0, stream>>>(vb, wvt, bv_c, vtb, 2, flag);

  attn_k<<<dim3(SEQ / 128, BATCH * NHEAD), dim3(512), 0, stream>>>(
      qh, kh, vtb, maskf, attB, attF, ctx, flag);

  proj_gemm<<<gp, tb, 0, stream>>>(ctx, wot, bo_c, d_out, 0, flag);
}